// Round 4
// baseline (173.801 us; speedup 1.0000x reference)
//
#include <hip/hip_runtime.h>
#include <math.h>

#define LR 0.001f

// Sizes
#define B   64
#define IN  2048
#define HID 512
#define OUT 128
#define QC  32          // q-chunks for layer-1 partials
#define QROWS (IN/QC)   // 64 q rows per block

typedef float vf2 __attribute__((ext_vector_type(2)));
typedef float vf4 __attribute__((ext_vector_type(4)));

// ws layout (floats)
#define WS_ZP    0                       // [B][QC][HID] = 1048576
#define WS_TANH  (WS_ZP + B*QC*HID)      // [B][HID]     = 32768
#define WS_ZOP   (WS_TANH + B*HID)       // [B][8][OUT]  = 65536
#define WS_GB    (WS_ZOP + B*8*OUT)      // [B][HID]     = 32768

// out layout (floats)
#define O_L2N   0
#define O_DW0   (B*OUT)
#define O_DB0   (O_DW0 + B*IN*HID)
#define O_DW1   (O_DB0 + B*HID)
#define O_DB1   (O_DW1 + B*HID*OUT)

// ---- layer-1 forward partials: zp[b,qc,h] = sum_{q in chunk} x[b,q]*(W0[q,h]+dW0[b,q,h])
// grid (B, QC), block 128; each thread owns 4 h (float4); two independent
// q-streams per thread (q and q+32) for 2x outstanding loads.
__global__ void k_fwd1(const float* __restrict__ x, const float* __restrict__ W0,
                       const float* __restrict__ dW0, float* __restrict__ zp) {
    const int b = blockIdx.x;
    const int q0 = blockIdx.y * QROWS;
    const int h = threadIdx.x * 4;        // 0..508
    const float* xr = x + b * IN;
    float4 acc0 = make_float4(0.f, 0.f, 0.f, 0.f);
    float4 acc1 = make_float4(0.f, 0.f, 0.f, 0.f);
    #pragma unroll 4
    for (int qi = 0; qi < QROWS / 2; ++qi) {
        const int qa = q0 + qi;
        const int qb = qa + QROWS / 2;
        const float xa = xr[qa];
        const float xb = xr[qb];
        const float4 w0a = *(const float4*)(W0 + qa * HID + h);
        const float4 dwa = *(const float4*)(dW0 + ((size_t)(b * IN + qa)) * HID + h);
        const float4 w0b = *(const float4*)(W0 + qb * HID + h);
        const float4 dwb = *(const float4*)(dW0 + ((size_t)(b * IN + qb)) * HID + h);
        acc0.x += xa * (w0a.x + dwa.x);
        acc0.y += xa * (w0a.y + dwa.y);
        acc0.z += xa * (w0a.z + dwa.z);
        acc0.w += xa * (w0a.w + dwa.w);
        acc1.x += xb * (w0b.x + dwb.x);
        acc1.y += xb * (w0b.y + dwb.y);
        acc1.z += xb * (w0b.z + dwb.z);
        acc1.w += xb * (w0b.w + dwb.w);
    }
    float4 acc;
    acc.x = acc0.x + acc1.x;
    acc.y = acc0.y + acc1.y;
    acc.z = acc0.z + acc1.z;
    acc.w = acc0.w + acc1.w;
    *(float4*)(zp + (b * QC + blockIdx.y) * HID + h) = acc;
}

// ---- layer-2 forward (+ fused bias/tanh): zop[b,yc,o] = sum_h tanh[b,h]*(W1[h,o]+dW1[b,h,o])
// grid (B, 8), block 128; each block owns 64 h rows, one o per thread.
__global__ void k_fwd2(const float* __restrict__ zp, const float* __restrict__ b0,
                       const float* __restrict__ db0, const float* __restrict__ W1,
                       const float* __restrict__ dW1, float* __restrict__ tanhv,
                       float* __restrict__ zop) {
    const int b = blockIdx.x;
    const int h0 = blockIdx.y * 64;
    const int tid = threadIdx.x;
    __shared__ float sth[64];
    if (tid < 64) {
        const int h = h0 + tid;
        float zsum = 0.f;
        const float* p = zp + (b * QC) * HID + h;
        #pragma unroll
        for (int qc = 0; qc < QC; ++qc) zsum += p[qc * HID];
        const float th = tanhf(zsum + b0[h] + db0[b * HID + h]);
        tanhv[b * HID + h] = th;
        sth[tid] = th;
    }
    __syncthreads();
    const int o = tid;
    float acc = 0.f;
    #pragma unroll 8
    for (int hi = 0; hi < 64; ++hi) {
        const int h = h0 + hi;
        acc += sth[hi] * (W1[h * OUT + o] + dW1[(b * HID + h) * OUT + o]);
    }
    zop[(b * 8 + blockIdx.y) * OUT + o] = acc;
}

// ---- fused middle + backward layer 2:
// recompute row stats per wave (redundant, cheap), g_b2, then g_b, new_dW1, new_db0;
// block (b, y==0) wave 0 also writes l2_normed_out2 and new_d_bias_1.
// grid (B, 8), block 256 (4 waves); each wave owns 16 h rows; lane owns 2 o.
__global__ void k_bwd1(const float* __restrict__ zop, const float* __restrict__ b1,
                       const float* __restrict__ db1, const float* __restrict__ ut,
                       const float* __restrict__ W1, const float* __restrict__ dW1,
                       const float* __restrict__ tanhv, const float* __restrict__ db0,
                       float* __restrict__ out_l2n, float* __restrict__ out_db1,
                       float* __restrict__ out_dW1, float* __restrict__ out_db0,
                       float* __restrict__ gb) {
    const int b = blockIdx.x;
    const int w = threadIdx.x >> 6;
    const int lane = threadIdx.x & 63;
    const int o2 = lane * 2;

    // out2 at (o2, o2+1) + full-row reductions (each wave redundantly)
    float2 zo;
    zo.x = b1[o2]     + db1[b * OUT + o2];
    zo.y = b1[o2 + 1] + db1[b * OUT + o2 + 1];
    #pragma unroll
    for (int c = 0; c < 8; ++c) {
        const float2 zp2 = *(const float2*)(zop + (b * 8 + c) * OUT + o2);
        zo.x += zp2.x; zo.y += zp2.y;
    }
    const float2 tr = *(const float2*)(ut + b * OUT + o2);
    float a = zo.x * zo.x + zo.y * zo.y;
    float c2 = tr.x * tr.x + tr.y * tr.y;
    float d  = tr.x * zo.x + tr.y * zo.y;
    for (int off = 32; off; off >>= 1) {
        a  += __shfl_xor(a,  off, 64);
        c2 += __shfl_xor(c2, off, 64);
        d  += __shfl_xor(d,  off, 64);
    }
    const float l2 = a;                               // squared norm (as in source)
    const float nt = fmaxf(sqrtf(c2), 1e-12f);        // ||update_target||
    const float tdot = d / nt;                        // sum(t * out2)
    const float s = 2.0f * tdot / (l2 * l2);
    float2 g2;
    g2.x = -(tr.x / nt) / l2 + s * zo.x;
    g2.y = -(tr.y / nt) / l2 + s * zo.y;

    if (blockIdx.y == 0 && w == 0) {
        *(float2*)(out_l2n + b * OUT + o2) = make_float2(zo.x / l2, zo.y / l2);
        *(float2*)(out_db1 + b * OUT + o2) =
            make_float2(db1[b * OUT + o2] - LR * g2.x, db1[b * OUT + o2 + 1] - LR * g2.y);
    }

    // backward through layer 2
    for (int i = 0; i < 16; ++i) {
        const int h = blockIdx.y * 64 + w * 16 + i;
        const int idx = (b * HID + h) * OUT + o2;
        const float2 dw = *(const float2*)(dW1 + idx);
        const float2 w1 = *(const float2*)(W1 + h * OUT + o2);
        float part = g2.x * (w1.x + dw.x) + g2.y * (w1.y + dw.y);
        for (int off = 32; off; off >>= 1) part += __shfl_xor(part, off, 64);
        const float th = tanhv[b * HID + h];
        vf2 nd;
        nd.x = dw.x - LR * th * g2.x;
        nd.y = dw.y - LR * th * g2.y;
        __builtin_nontemporal_store(nd, (vf2*)(out_dW1 + idx));
        if (lane == 0) {
            const float gbv = (1.f - th * th) * part;
            gb[b * HID + h] = gbv;
            out_db0[b * HID + h] = db0[b * HID + h] - LR * gbv;
        }
    }
}

// ---- new_d_weights_0 = dW0 - LR * x[b,q] * gb[b,h]
// dW0 is exactly 256 MiB == L3 size; most of it is still L3-resident after
// k_fwd1, so the read here is largely L3 hits. Nontemporal stores keep the
// 268MB output stream from evicting those lines.
__global__ void k_upd0(const float* __restrict__ dW0, const float* __restrict__ x,
                       const float* __restrict__ gb, float* __restrict__ out_dW0) {
    const int n4 = B * IN * HID / 4;     // 16,777,216
    const int stride = gridDim.x * blockDim.x;
    for (int i = blockIdx.x * blockDim.x + threadIdx.x; i < n4; i += stride) {
        const int h4 = i & (HID / 4 - 1);        // 0..127
        const int rest = i >> 7;
        const int q = rest & (IN - 1);
        const int b = rest >> 11;
        const float4 dw = ((const float4*)dW0)[i];
        const float xv = x[b * IN + q];
        const float4 g = *(const float4*)(gb + b * HID + h4 * 4);
        vf4 o;
        o.x = dw.x - LR * xv * g.x;
        o.y = dw.y - LR * xv * g.y;
        o.z = dw.z - LR * xv * g.z;
        o.w = dw.w - LR * xv * g.w;
        __builtin_nontemporal_store(o, (vf4*)out_dW0 + i);
    }
}

extern "C" void kernel_launch(void* const* d_in, const int* in_sizes, int n_in,
                              void* d_out, int out_size, void* d_ws, size_t ws_size,
                              hipStream_t stream) {
    (void)in_sizes; (void)n_in; (void)out_size; (void)ws_size;
    const float* x   = (const float*)d_in[0];
    const float* ut  = (const float*)d_in[1];
    const float* W0  = (const float*)d_in[2];
    const float* b0  = (const float*)d_in[3];
    const float* W1  = (const float*)d_in[4];
    const float* b1  = (const float*)d_in[5];
    const float* dW0 = (const float*)d_in[6];
    const float* db0 = (const float*)d_in[7];
    const float* dW1 = (const float*)d_in[8];
    const float* db1 = (const float*)d_in[9];

    float* ws  = (float*)d_ws;
    float* out = (float*)d_out;

    k_fwd1<<<dim3(B, QC), 128, 0, stream>>>(x, W0, dW0, ws + WS_ZP);
    k_fwd2<<<dim3(B, 8), 128, 0, stream>>>(ws + WS_ZP, b0, db0, W1, dW1,
                                           ws + WS_TANH, ws + WS_ZOP);
    k_bwd1<<<dim3(B, 8), 256, 0, stream>>>(ws + WS_ZOP, b1, db1, ut, W1, dW1,
                                           ws + WS_TANH, db0,
                                           out + O_L2N, out + O_DB1,
                                           out + O_DW1, out + O_DB0, ws + WS_GB);
    k_upd0<<<dim3(8192), 256, 0, stream>>>(dW0, x, ws + WS_GB, out + O_DW0);
}